// Round 4
// baseline (471.732 us; speedup 1.0000x reference)
//
#include <hip/hip_runtime.h>
#include <hip/hip_bf16.h>

#define NN 6144
#define INPUT 1024
#define HID 256

using frag  = __attribute__((ext_vector_type(8))) short;   // 8 bf16
using f32x4 = __attribute__((ext_vector_type(4))) float;

union fragcvt { frag f; __hip_bfloat162 h[4]; };

static __device__ __forceinline__ frag pack8(float p0, float p1, float p2, float p3,
                                             float p4, float p5, float p6, float p7) {
    fragcvt u;
    u.h[0] = __float22bfloat162_rn(make_float2(p0, p1));
    u.h[1] = __float22bfloat162_rn(make_float2(p2, p3));
    u.h[2] = __float22bfloat162_rn(make_float2(p4, p5));
    u.h[3] = __float22bfloat162_rn(make_float2(p6, p7));
    return u.f;
}

static __device__ __forceinline__ unsigned short bf16u(float x) {
    unsigned u = __float_as_uint(x);
    u += 0x7fff + ((u >> 16) & 1);     // RNE
    return (unsigned short)(u >> 16);
}

// ---------------- convert W -> Wt bf16 transposed [HID][INPUT] ----------------
__global__ __launch_bounds__(256) void k_convert_w(const float* __restrict__ W,
                                                   unsigned short* __restrict__ Wt) {
    int t = blockIdx.x * 256 + threadIdx.x;          // t = n*1024 + k
    int n = t >> 10, k = t & 1023;
    Wt[t] = bf16u(W[k * HID + n]);
}

// ---------------- GEMM1: hT = (X @ W)^T bf16, + fused s1/s2 ----------------
// grid 384; block 256 = 4 waves, ALL waves share rows i0..i0+15 (adj-free, X L1-shared),
// wave w covers n = w*64..w*64+63 (4 B-frags). No LDS, no barriers; depth-1 prefetch.
__global__ __launch_bounds__(256) void k_gemm1(const float* __restrict__ X,
                                               const unsigned short* __restrict__ Wt,
                                               const float* __restrict__ a_edge,
                                               unsigned short* __restrict__ hT,
                                               float* __restrict__ s1,
                                               float* __restrict__ s2) {
    int t = threadIdx.x, w = t >> 6, l = t & 63, lm = l & 15, q = l >> 4;
    int i0 = blockIdx.x * 16;
    int n0 = w * 64;

    const float* xp = X + (size_t)(i0 + lm) * INPUT + q * 8;
    const unsigned short* wp = Wt + (size_t)(n0 + lm) * INPUT + q * 8;
    const int WS = 16 * INPUT;

    f32x4 acc[4] = {};
    float4 cx0 = *reinterpret_cast<const float4*>(xp);
    float4 cx1 = *reinterpret_cast<const float4*>(xp + 4);
    frag cw0 = *reinterpret_cast<const frag*>(wp);
    frag cw1 = *reinterpret_cast<const frag*>(wp + WS);
    frag cw2 = *reinterpret_cast<const frag*>(wp + 2 * WS);
    frag cw3 = *reinterpret_cast<const frag*>(wp + 3 * WS);

#pragma unroll 2
    for (int it = 0; it < 32; it++) {
        int kn = ((it < 31) ? (it + 1) : it) * 32;
        float4 nx0 = *reinterpret_cast<const float4*>(xp + kn);
        float4 nx1 = *reinterpret_cast<const float4*>(xp + kn + 4);
        frag nw0 = *reinterpret_cast<const frag*>(wp + kn);
        frag nw1 = *reinterpret_cast<const frag*>(wp + WS + kn);
        frag nw2 = *reinterpret_cast<const frag*>(wp + 2 * WS + kn);
        frag nw3 = *reinterpret_cast<const frag*>(wp + 3 * WS + kn);

        frag af = pack8(cx0.x, cx0.y, cx0.z, cx0.w, cx1.x, cx1.y, cx1.z, cx1.w);
        acc[0] = __builtin_amdgcn_mfma_f32_16x16x32_bf16(af, cw0, acc[0], 0, 0, 0);
        acc[1] = __builtin_amdgcn_mfma_f32_16x16x32_bf16(af, cw1, acc[1], 0, 0, 0);
        acc[2] = __builtin_amdgcn_mfma_f32_16x16x32_bf16(af, cw2, acc[2], 0, 0, 0);
        acc[3] = __builtin_amdgcn_mfma_f32_16x16x32_bf16(af, cw3, acc[3], 0, 0, 0);

        cx0 = nx0; cx1 = nx1; cw0 = nw0; cw1 = nw1; cw2 = nw2; cw3 = nw3;
    }

    // hT write: C/D layout col(n-within-frag)=lm, row(m)=q*4+r; hT[n][i]
#pragma unroll
    for (int nt = 0; nt < 4; nt++) {
        ushort4 o;
        o.x = bf16u(acc[nt][0]); o.y = bf16u(acc[nt][1]);
        o.z = bf16u(acc[nt][2]); o.w = bf16u(acc[nt][3]);
        *reinterpret_cast<ushort4*>(hT + (size_t)(n0 + nt * 16 + lm) * NN + i0 + q * 4) = o;
    }

    // fused s1/s2: per row i0+q*4+r, sum over this wave's 64 n
    float a1v0 = a_edge[n0 + lm],            a1v1 = a_edge[n0 + 16 + lm];
    float a1v2 = a_edge[n0 + 32 + lm],       a1v3 = a_edge[n0 + 48 + lm];
    float a2v0 = a_edge[HID + n0 + lm],      a2v1 = a_edge[HID + n0 + 16 + lm];
    float a2v2 = a_edge[HID + n0 + 32 + lm], a2v3 = a_edge[HID + n0 + 48 + lm];
#pragma unroll
    for (int r = 0; r < 4; r++) {
        float v1 = acc[0][r] * a1v0 + acc[1][r] * a1v1 + acc[2][r] * a1v2 + acc[3][r] * a1v3;
        float v2 = acc[0][r] * a2v0 + acc[1][r] * a2v1 + acc[2][r] * a2v2 + acc[3][r] * a2v3;
        v1 += __shfl_xor(v1, 1); v2 += __shfl_xor(v2, 1);
        v1 += __shfl_xor(v1, 2); v2 += __shfl_xor(v2, 2);
        v1 += __shfl_xor(v1, 4); v2 += __shfl_xor(v2, 4);
        v1 += __shfl_xor(v1, 8); v2 += __shfl_xor(v2, 8);
        if (lm == 0) {
            atomicAdd(&s1[i0 + q * 4 + r], v1);
            atomicAdd(&s2[i0 + q * 4 + r], v2);
        }
    }
}

// ---------------- fused attention: no LDS, no barriers, no atomics ----------------
// grid (384, 2); block 256 = 4 waves sharing rows i0..i0+15 (adj loads L1-shared);
// wave w: n = w*64..w*64+63; j-half of 3072 = 96 K-steps of 32.
// Lane builds its own A-frag: A[m=lm][k=q*8+e] = p(i0+lm, j+q*8+e).
__global__ __launch_bounds__(256, 3) void k_attn(const int* __restrict__ adj,
                                                 const float* __restrict__ s1,
                                                 const float* __restrict__ s2,
                                                 const unsigned short* __restrict__ hT,
                                                 float* __restrict__ U2,
                                                 float* __restrict__ denom2) {
    int t = threadIdx.x, w = t >> 6, l = t & 63, lm = l & 15, q = l >> 4;
    int i0 = blockIdx.x * 16;
    int jh = blockIdx.y;
    int j0 = jh * 3072;
    int row = i0 + lm;

    float s1v = s1[row];
    const int*   ap = adj + (size_t)row * NN + j0 + q * 8;
    const float* sp = s2 + j0 + q * 8;
    const unsigned short* bp = hT + (size_t)(w * 64 + lm) * NN + j0 + q * 8;
    const int BS = 16 * NN;

    f32x4 acc[4] = {};
    float dsum = 0.f;

    int4   ca0 = *reinterpret_cast<const int4*>(ap);
    int4   ca1 = *reinterpret_cast<const int4*>(ap + 4);
    float4 cs0 = *reinterpret_cast<const float4*>(sp);
    float4 cs1 = *reinterpret_cast<const float4*>(sp + 4);
    frag cb0 = *reinterpret_cast<const frag*>(bp);
    frag cb1 = *reinterpret_cast<const frag*>(bp + BS);
    frag cb2 = *reinterpret_cast<const frag*>(bp + 2 * BS);
    frag cb3 = *reinterpret_cast<const frag*>(bp + 3 * BS);

#pragma unroll 2
    for (int it = 0; it < 96; it++) {
        int kn = ((it < 95) ? (it + 1) : it) * 32;
        int4   na0 = *reinterpret_cast<const int4*>(ap + kn);
        int4   na1 = *reinterpret_cast<const int4*>(ap + kn + 4);
        float4 ns0 = *reinterpret_cast<const float4*>(sp + kn);
        float4 ns1 = *reinterpret_cast<const float4*>(sp + kn + 4);
        frag nb0 = *reinterpret_cast<const frag*>(bp + kn);
        frag nb1 = *reinterpret_cast<const frag*>(bp + BS + kn);
        frag nb2 = *reinterpret_cast<const frag*>(bp + 2 * BS + kn);
        frag nb3 = *reinterpret_cast<const frag*>(bp + 3 * BS + kn);

        float sc, e, p0, p1, p2, p3, p4, p5, p6, p7;
        sc = s1v + cs0.x; e = __expf(fmaxf(sc, 0.2f * sc)); p0 = ca0.x ? e : 0.f;
        sc = s1v + cs0.y; e = __expf(fmaxf(sc, 0.2f * sc)); p1 = ca0.y ? e : 0.f;
        sc = s1v + cs0.z; e = __expf(fmaxf(sc, 0.2f * sc)); p2 = ca0.z ? e : 0.f;
        sc = s1v + cs0.w; e = __expf(fmaxf(sc, 0.2f * sc)); p3 = ca0.w ? e : 0.f;
        sc = s1v + cs1.x; e = __expf(fmaxf(sc, 0.2f * sc)); p4 = ca1.x ? e : 0.f;
        sc = s1v + cs1.y; e = __expf(fmaxf(sc, 0.2f * sc)); p5 = ca1.y ? e : 0.f;
        sc = s1v + cs1.z; e = __expf(fmaxf(sc, 0.2f * sc)); p6 = ca1.z ? e : 0.f;
        sc = s1v + cs1.w; e = __expf(fmaxf(sc, 0.2f * sc)); p7 = ca1.w ? e : 0.f;
        dsum += ((p0 + p1) + (p2 + p3)) + ((p4 + p5) + (p6 + p7));

        frag af = pack8(p0, p1, p2, p3, p4, p5, p6, p7);
        acc[0] = __builtin_amdgcn_mfma_f32_16x16x32_bf16(af, cb0, acc[0], 0, 0, 0);
        acc[1] = __builtin_amdgcn_mfma_f32_16x16x32_bf16(af, cb1, acc[1], 0, 0, 0);
        acc[2] = __builtin_amdgcn_mfma_f32_16x16x32_bf16(af, cb2, acc[2], 0, 0, 0);
        acc[3] = __builtin_amdgcn_mfma_f32_16x16x32_bf16(af, cb3, acc[3], 0, 0, 0);

        ca0 = na0; ca1 = na1; cs0 = ns0; cs1 = ns1;
        cb0 = nb0; cb1 = nb1; cb2 = nb2; cb3 = nb3;
    }

    // denom: reduce dsum over q (same lm covers all 32 cols/step); waves redundant -> w0 stores
    dsum += __shfl_xor(dsum, 16);
    dsum += __shfl_xor(dsum, 32);
    if (w == 0 && q == 0) denom2[(size_t)jh * NN + row] = dsum;

    // U2 partial: plain disjoint stores
    float* Ub = U2 + (size_t)jh * NN * HID;
#pragma unroll
    for (int nt = 0; nt < 4; nt++)
#pragma unroll
        for (int r = 0; r < 4; r++)
            Ub[(size_t)(i0 + q * 4 + r) * HID + w * 64 + nt * 16 + lm] = acc[nt][r];
}

// ---------------- normalize: out = (U2[0]+U2[1]) / (denom2[0]+denom2[1]) ----------------
__global__ __launch_bounds__(256) void k_norm(const float* __restrict__ U2,
                                              const float* __restrict__ denom2,
                                              float* __restrict__ out) {
    int i = blockIdx.x, t = threadIdx.x;
    size_t S = (size_t)NN * HID;
    size_t base = (size_t)i * HID + t;
    float u = U2[base] + U2[base + S];
    float d = denom2[i] + denom2[i + NN];
    out[base] = (d != 0.f) ? u / d : 0.f;
}

extern "C" void kernel_launch(void* const* d_in, const int* in_sizes, int n_in,
                              void* d_out, int out_size, void* d_ws, size_t ws_size,
                              hipStream_t stream) {
    const float* X      = (const float*)d_in[0];   // 6144x1024
    const float* W      = (const float*)d_in[1];   // 1024x256
    const float* a_edge = (const float*)d_in[2];   // 512
    const int*   adj    = (const int*)d_in[3];     // 6144x6144
    float* out = (float*)d_out;

    float* U2     = (float*)d_ws;                        // 2*NN*HID f32 (12.6 MB)
    float* denom2 = U2 + (size_t)2 * NN * HID;           // 2*NN
    float* s1     = denom2 + 2 * NN;                     // NN
    float* s2     = s1 + NN;                             // NN
    unsigned short* hT = (unsigned short*)(s2 + NN);     // HID*NN bf16 (3.1 MB)
    unsigned short* Wt = hT + (size_t)HID * NN;          // HID*INPUT bf16 (0.5 MB)

    hipMemsetAsync(s1, 0, 2 * NN * sizeof(float), stream);
    k_convert_w<<<INPUT * HID / 256, 256, 0, stream>>>(W, Wt);
    k_gemm1<<<NN / 16, 256, 0, stream>>>(X, Wt, a_edge, hT, s1, s2);
    k_attn<<<dim3(NN / 16, 2), 256, 0, stream>>>(adj, s1, s2, hT, U2, denom2);
    k_norm<<<NN, 256, 0, stream>>>(U2, denom2, out);
}

// Round 5
// 357.919 us; speedup vs baseline: 1.3180x; 1.3180x over previous
//
#include <hip/hip_runtime.h>
#include <hip/hip_bf16.h>

#define NN 6144
#define INPUT 1024
#define HID 256

using frag  = __attribute__((ext_vector_type(8))) short;   // 8 bf16
using f32x4 = __attribute__((ext_vector_type(4))) float;

union fragcvt { frag f; __hip_bfloat162 h[4]; };

static __device__ __forceinline__ frag pack8(float p0, float p1, float p2, float p3,
                                             float p4, float p5, float p6, float p7) {
    fragcvt u;
    u.h[0] = __float22bfloat162_rn(make_float2(p0, p1));
    u.h[1] = __float22bfloat162_rn(make_float2(p2, p3));
    u.h[2] = __float22bfloat162_rn(make_float2(p4, p5));
    u.h[3] = __float22bfloat162_rn(make_float2(p6, p7));
    return u.f;
}

static __device__ __forceinline__ unsigned short bf16u(float x) {
    unsigned u = __float_as_uint(x);
    u += 0x7fff + ((u >> 16) & 1);     // RNE
    return (unsigned short)(u >> 16);
}

// ---------------- convert W -> Wt bf16 transposed [HID][INPUT] ----------------
__global__ __launch_bounds__(256) void k_convert_w(const float* __restrict__ W,
                                                   unsigned short* __restrict__ Wt) {
    int t = blockIdx.x * 256 + threadIdx.x;          // t = n*1024 + k
    int n = t >> 10, k = t & 1023;
    Wt[t] = bf16u(W[k * HID + n]);
}

// ---------------- GEMM1: hT = (X @ W)^T bf16, + fused s1/s2 (R2 version, verified) ----------------
__global__ __launch_bounds__(256) void k_gemm1(const float* __restrict__ X,
                                               const unsigned short* __restrict__ Wt,
                                               const float* __restrict__ a_edge,
                                               unsigned short* __restrict__ hT,
                                               float* __restrict__ s1,
                                               float* __restrict__ s2) {
    __shared__ unsigned short A[2][32][72];
    int t = threadIdx.x;
    int m = t >> 3, cg = t & 7;
    int i0 = blockIdx.x * 32, n0 = blockIdx.y * 64;
    int w = t >> 6, l = t & 63, lm = l & 15, q = l >> 4;
    int nw = n0 + w * 16;

    const float* xrow = X + (size_t)(i0 + m) * INPUT + cg * 8;
    const unsigned short* brow = Wt + (size_t)(nw + lm) * INPUT + q * 8;

    f32x4 acc0 = {}, acc1 = {};

    for (int c = 0; c < 16; c++) {
        int buf = c & 1;
        float4 xa = *reinterpret_cast<const float4*>(xrow + c * 64);
        float4 xb = *reinterpret_cast<const float4*>(xrow + c * 64 + 4);
        frag av;
        av[0] = (short)bf16u(xa.x); av[1] = (short)bf16u(xa.y);
        av[2] = (short)bf16u(xa.z); av[3] = (short)bf16u(xa.w);
        av[4] = (short)bf16u(xb.x); av[5] = (short)bf16u(xb.y);
        av[6] = (short)bf16u(xb.z); av[7] = (short)bf16u(xb.w);
        *reinterpret_cast<frag*>(&A[buf][m][cg * 8]) = av;

        __syncthreads();

#pragma unroll
        for (int kk = 0; kk < 2; kk++) {
            frag a0 = *reinterpret_cast<const frag*>(&A[buf][lm][kk * 32 + q * 8]);
            frag a1 = *reinterpret_cast<const frag*>(&A[buf][16 + lm][kk * 32 + q * 8]);
            frag b  = *reinterpret_cast<const frag*>(brow + c * 64 + kk * 32);
            acc0 = __builtin_amdgcn_mfma_f32_16x16x32_bf16(a0, b, acc0, 0, 0, 0);
            acc1 = __builtin_amdgcn_mfma_f32_16x16x32_bf16(a1, b, acc1, 0, 0, 0);
        }
    }

    ushort4 o;
    o.x = bf16u(acc0[0]); o.y = bf16u(acc0[1]); o.z = bf16u(acc0[2]); o.w = bf16u(acc0[3]);
    *reinterpret_cast<ushort4*>(hT + (size_t)(nw + lm) * NN + i0 + q * 4) = o;
    o.x = bf16u(acc1[0]); o.y = bf16u(acc1[1]); o.z = bf16u(acc1[2]); o.w = bf16u(acc1[3]);
    *reinterpret_cast<ushort4*>(hT + (size_t)(nw + lm) * NN + i0 + 16 + q * 4) = o;

    float a1v = a_edge[nw + lm], a2v = a_edge[HID + nw + lm];
#pragma unroll
    for (int h = 0; h < 2; h++) {
        const f32x4& ac = h ? acc1 : acc0;
#pragma unroll
        for (int r = 0; r < 4; r++) {
            float v1 = ac[r] * a1v, v2 = ac[r] * a2v;
            v1 += __shfl_xor(v1, 1); v2 += __shfl_xor(v2, 1);
            v1 += __shfl_xor(v1, 2); v2 += __shfl_xor(v2, 2);
            v1 += __shfl_xor(v1, 4); v2 += __shfl_xor(v2, 4);
            v1 += __shfl_xor(v1, 8); v2 += __shfl_xor(v2, 8);
            if (lm == 0) {
                atomicAdd(&s1[i0 + h * 16 + q * 4 + r], v1);
                atomicAdd(&s2[i0 + h * 16 + q * 4 + r], v2);
            }
        }
    }
}

// ---------------- fused attention ----------------
// grid (192, nj); block 256 = 4 waves. M=32 rows/block, colsPer = NN/nj per block,
// chunks of 128 cols. Builder thread (w=kk, l) builds EXACTLY the A-frag that lane l
// of consumer wave kk reads: both LDS accesses are lane-contiguous 16 B (conflict-free).
// All 6 build loads batched up front -> one exposed latency per chunk.
__global__ __launch_bounds__(256, 5) void k_attn(const int* __restrict__ adj,
                                                 const float* __restrict__ s1,
                                                 const float* __restrict__ s2,
                                                 const unsigned short* __restrict__ hT,
                                                 float* __restrict__ Up,
                                                 float* __restrict__ denomp,
                                                 int colsPer) {
    __shared__ unsigned short PF[2][4][2][64][8];   // [buf][kk][frag][lane][8] = 16 KB
    __shared__ float dred[4][32];

    int t = threadIdx.x;
    int w = t >> 6, l = t & 63, lm = l & 15, q = l >> 4;
    int i0 = blockIdx.x * 32;
    int jh = blockIdx.y;
    int j0 = jh * colsPer;
    int nchunk = colsPer >> 7;
    int r0 = i0 + lm, r1 = r0 + 16;

    float s1v0 = s1[r0], s1v1 = s1[r1];
    const int*   ap0 = adj + (size_t)r0 * NN + j0 + w * 32 + q * 8;
    const int*   ap1 = adj + (size_t)r1 * NN + j0 + w * 32 + q * 8;
    const float* sp  = s2 + j0 + w * 32 + q * 8;
    const unsigned short* bp = hT + (size_t)(w * 64 + lm) * NN + j0 + q * 8;

    f32x4 acc[2][4] = {};
    float d0 = 0.f, d1 = 0.f;

    for (int c = 0; c < nchunk; c++) {
        int buf = c & 1, jc = c * 128;
        // ---- batched loads: all 6 issued before any use ----
        int4   a00 = *reinterpret_cast<const int4*>(ap0 + jc);
        int4   a01 = *reinterpret_cast<const int4*>(ap0 + jc + 4);
        int4   a10 = *reinterpret_cast<const int4*>(ap1 + jc);
        int4   a11 = *reinterpret_cast<const int4*>(ap1 + jc + 4);
        float4 sv0 = *reinterpret_cast<const float4*>(sp + jc);
        float4 sv1 = *reinterpret_cast<const float4*>(sp + jc + 4);

        float sc, e;
        float p0, p1, p2, p3, p4, p5, p6, p7;
        // frag0 (row r0)
        sc = s1v0 + sv0.x; e = __expf(fmaxf(sc, 0.2f * sc)); p0 = a00.x ? e : 0.f;
        sc = s1v0 + sv0.y; e = __expf(fmaxf(sc, 0.2f * sc)); p1 = a00.y ? e : 0.f;
        sc = s1v0 + sv0.z; e = __expf(fmaxf(sc, 0.2f * sc)); p2 = a00.z ? e : 0.f;
        sc = s1v0 + sv0.w; e = __expf(fmaxf(sc, 0.2f * sc)); p3 = a00.w ? e : 0.f;
        sc = s1v0 + sv1.x; e = __expf(fmaxf(sc, 0.2f * sc)); p4 = a01.x ? e : 0.f;
        sc = s1v0 + sv1.y; e = __expf(fmaxf(sc, 0.2f * sc)); p5 = a01.y ? e : 0.f;
        sc = s1v0 + sv1.z; e = __expf(fmaxf(sc, 0.2f * sc)); p6 = a01.z ? e : 0.f;
        sc = s1v0 + sv1.w; e = __expf(fmaxf(sc, 0.2f * sc)); p7 = a01.w ? e : 0.f;
        d0 += ((p0 + p1) + (p2 + p3)) + ((p4 + p5) + (p6 + p7));
        frag af0 = pack8(p0, p1, p2, p3, p4, p5, p6, p7);
        // frag1 (row r1)
        sc = s1v1 + sv0.x; e = __expf(fmaxf(sc, 0.2f * sc)); p0 = a10.x ? e : 0.f;
        sc = s1v1 + sv0.y; e = __expf(fmaxf(sc, 0.2f * sc)); p1 = a10.y ? e : 0.f;
        sc = s1v1 + sv0.z; e = __expf(fmaxf(sc, 0.2f * sc)); p2 = a10.z ? e : 0.f;
        sc = s1v1 + sv0.w; e = __expf(fmaxf(sc, 0.2f * sc)); p3 = a10.w ? e : 0.f;
        sc = s1v1 + sv1.x; e = __expf(fmaxf(sc, 0.2f * sc)); p4 = a11.x ? e : 0.f;
        sc = s1v1 + sv1.y; e = __expf(fmaxf(sc, 0.2f * sc)); p5 = a11.y ? e : 0.f;
        sc = s1v1 + sv1.z; e = __expf(fmaxf(sc, 0.2f * sc)); p6 = a11.z ? e : 0.f;
        sc = s1v1 + sv1.w; e = __expf(fmaxf(sc, 0.2f * sc)); p7 = a11.w ? e : 0.f;
        d1 += ((p0 + p1) + (p2 + p3)) + ((p4 + p5) + (p6 + p7));
        frag af1 = pack8(p0, p1, p2, p3, p4, p5, p6, p7);

        // lane-contiguous 16B writes (conflict-free)
        *reinterpret_cast<frag*>(&PF[buf][w][0][l][0]) = af0;
        *reinterpret_cast<frag*>(&PF[buf][w][1][l][0]) = af1;

        __syncthreads();

        // ---- consume: lane-contiguous 16B reads (conflict-free) ----
#pragma unroll
        for (int kk = 0; kk < 4; kk++) {
            frag a0 = *reinterpret_cast<const frag*>(&PF[buf][kk][0][l][0]);
            frag a1 = *reinterpret_cast<const frag*>(&PF[buf][kk][1][l][0]);
            const unsigned short* bb = bp + jc + kk * 32;
#pragma unroll
            for (int nt = 0; nt < 4; nt++) {
                frag b = *reinterpret_cast<const frag*>(bb + nt * 16 * NN);
                acc[0][nt] = __builtin_amdgcn_mfma_f32_16x16x32_bf16(a0, b, acc[0][nt], 0, 0, 0);
                acc[1][nt] = __builtin_amdgcn_mfma_f32_16x16x32_bf16(a1, b, acc[1][nt], 0, 0, 0);
            }
        }
        // single barrier per chunk: dbuf argument as in R2 (safe).
    }

    // denominator: reduce over q (lanes share lm), then across the 4 waves via LDS
    d0 += __shfl_xor(d0, 16); d0 += __shfl_xor(d0, 32);
    d1 += __shfl_xor(d1, 16); d1 += __shfl_xor(d1, 32);
    if (q == 0) { dred[w][lm] = d0; dred[w][16 + lm] = d1; }
    __syncthreads();
    if (t < 32)
        denomp[(size_t)jh * NN + i0 + t] = dred[0][t] + dred[1][t] + dred[2][t] + dred[3][t];

    // U partial: plain disjoint stores; C/D layout col=lm, row=q*4+r
    float* Ub = Up + (size_t)jh * NN * HID;
#pragma unroll
    for (int f = 0; f < 2; f++)
#pragma unroll
        for (int nt = 0; nt < 4; nt++)
#pragma unroll
            for (int r = 0; r < 4; r++)
                Ub[(size_t)(i0 + f * 16 + q * 4 + r) * HID + w * 64 + nt * 16 + lm] = acc[f][nt][r];
}

// ---------------- normalize: out = (sum_j Up[j]) / (sum_j denom[j]) ----------------
__global__ __launch_bounds__(256) void k_norm(const float* __restrict__ Up,
                                              const float* __restrict__ denomp,
                                              float* __restrict__ out, int nj) {
    int i = blockIdx.x, t = threadIdx.x;
    size_t S = (size_t)NN * HID;
    size_t base = (size_t)i * HID + t;
    float u = 0.f, d = 0.f;
    for (int j = 0; j < nj; j++) {
        u += Up[base + (size_t)j * S];
        d += denomp[i + (size_t)j * NN];
    }
    out[base] = (d != 0.f) ? u / d : 0.f;
}

extern "C" void kernel_launch(void* const* d_in, const int* in_sizes, int n_in,
                              void* d_out, int out_size, void* d_ws, size_t ws_size,
                              hipStream_t stream) {
    const float* X      = (const float*)d_in[0];   // 6144x1024
    const float* W      = (const float*)d_in[1];   // 1024x256
    const float* a_edge = (const float*)d_in[2];   // 512
    const int*   adj    = (const int*)d_in[3];     // 6144x6144
    float* out = (float*)d_out;

    // choose j-split count by available workspace
    auto need = [](int nj) -> size_t {
        return (size_t)4 * ((size_t)nj * NN * HID + (size_t)nj * NN + 2 * NN)
             + (size_t)2 * ((size_t)HID * NN + (size_t)HID * INPUT);
    };
    int nj = (ws_size >= need(8)) ? 8 : 4;
    int colsPer = NN / nj;

    float* Up     = (float*)d_ws;                          // nj*NN*HID f32
    float* denomp = Up + (size_t)nj * NN * HID;            // nj*NN
    float* s1     = denomp + (size_t)nj * NN;              // NN
    float* s2     = s1 + NN;                               // NN
    unsigned short* hT = (unsigned short*)(s2 + NN);       // HID*NN bf16
    unsigned short* Wt = hT + (size_t)HID * NN;            // HID*INPUT bf16

    hipMemsetAsync(s1, 0, 2 * NN * sizeof(float), stream);
    k_convert_w<<<INPUT * HID / 256, 256, 0, stream>>>(W, Wt);
    k_gemm1<<<dim3(NN / 32, HID / 64), 256, 0, stream>>>(X, Wt, a_edge, hT, s1, s2);
    k_attn<<<dim3(NN / 32, nj), 256, 0, stream>>>(adj, s1, s2, hT, Up, denomp, colsPer);
    k_norm<<<NN, 256, 0, stream>>>(Up, denomp, out, nj);
}